// Round 5
// baseline (285.544 us; speedup 1.0000x reference)
//
#include <hip/hip_runtime.h>
#include <hip/hip_bf16.h>
#include <cstddef>
#include <cstdint>

#define B_SZ   8
#define T_CTX  1024
#define C_DIM  1024
#define H_NUM  16
#define HS     64
#define M_ROWS (B_SZ * T_CTX)

typedef __attribute__((ext_vector_type(8))) short bf16x8;
typedef __attribute__((ext_vector_type(8))) unsigned short u16x8;
typedef __attribute__((ext_vector_type(4))) float f32x4;

static __device__ inline unsigned short f2bf(float f) {
    __hip_bfloat16 h = __float2bfloat16(f);
    return __builtin_bit_cast(unsigned short, h);
}
static __device__ inline float bf2f(unsigned short u) {
    unsigned int v = ((unsigned int)u) << 16;
    return __builtin_bit_cast(float, v);
}
static __device__ inline void gld16(const void* g, void* l) {
    __builtin_amdgcn_global_load_lds((const __attribute__((address_space(1))) void*)g,
                                     (__attribute__((address_space(3))) void*)l,
                                     16, 0, 0);
}

// ---------------------------------------------------------------------------
// Fused conversion: blocks [0,8192) do x->xs (bf16, time-shifted);
// blocks [8192,12288) do the 4 weight matrices -> stacked bf16.
// ---------------------------------------------------------------------------
__global__ __launch_bounds__(256)
void convert_all(const float* __restrict__ x, unsigned short* __restrict__ xs,
                 const float* __restrict__ Wk, const float* __restrict__ Wv,
                 const float* __restrict__ Wr, const float* __restrict__ Wo,
                 unsigned short* __restrict__ wdst)
{
    const int bid = blockIdx.x;
    if (bid < 8192) {
        const int idx = (bid * 256 + threadIdx.x) * 4;
        const int m = idx >> 10;
        const int c = idx & 1023;
        float4 v;
        if (c < 512) {
            const int t = m & (T_CTX - 1);
            if (t == 0) v = make_float4(0.f, 0.f, 0.f, 0.f);
            else        v = *(const float4*)(x + (size_t)(m - 1) * C_DIM + c);
        } else {
            v = *(const float4*)(x + idx);
        }
        ushort4 o;
        o.x = f2bf(v.x); o.y = f2bf(v.y); o.z = f2bf(v.z); o.w = f2bf(v.w);
        *(ushort4*)(xs + idx) = o;
    } else {
        const int wid = bid - 8192;
        const int z = wid >> 10;
        const float* src = (z == 0) ? Wk : (z == 1) ? Wv : (z == 2) ? Wr : Wo;
        const int idx = ((wid & 1023) * 256 + threadIdx.x) * 4;
        const float4 v = *(const float4*)(src + idx);
        ushort4 o;
        o.x = f2bf(v.x); o.y = f2bf(v.y); o.z = f2bf(v.z); o.w = f2bf(v.w);
        *(ushort4*)(wdst + (size_t)z * (C_DIM * C_DIM) + idx) = o;
    }
}

// ---------------------------------------------------------------------------
// 8-phase-style pipelined bf16 MFMA GEMM (big projection GEMM only).
// BM=128 x BN=256, BK=64, 512 thr = 8 waves (2Mx4N), per-wave 64x64 (acc[4][4]).
// Ring-of-3 dbufs: A 3x16KB + B 3x32KB = 144 KiB. Iter kt consumes dbuf kt%3
// and stages tile kt+2 into dbuf (kt+2)%3 (free: its last reads drained at
// iter kt-1 P3's lgkm(0)+barrier).
// 4 phases per K-tile, template ordering: {ds_reads ; 1 stage unit} BEFORE
// barrier -> barrier -> lgkmcnt(0) -> setprio(1) 8xMFMA setprio(0) -> barrier.
// Counted vmcnt ONCE per K-tile at P3 (before its first barrier):
//   outstanding = tile kt+1 (6 loads) + tile kt+2 (6 just issued) = 12
//   -> vmcnt(6) drains exactly tile kt+1 (consumed next iter). Tail: kt=14
//   -> vmcnt(0); kt=15 none. Prologue stages tiles 0,1 then vmcnt(6)+barrier.
// Swizzle (both-sides): phys 16B chunk of row = log ^ (row&7), carried by
// pre-swizzled global source (gld16 dest stays linear); frag reads are
// 2-way bank aliased only (free).
// Grid 768 = 64 ty x 12 tx, bijective XCD chunking (chunk=96).
// Epilogue fused per z = n0>>10: 0 exp(clip)->fp32, 1 id->bf16, 2 sigmoid->bf16.
// ---------------------------------------------------------------------------
__global__ __launch_bounds__(512, 1)
void mfma_gemm8p(const unsigned short* __restrict__ A,
                 const unsigned short* __restrict__ Wb,
                 const float* __restrict__ b0, const float* __restrict__ b1,
                 const float* __restrict__ b2,
                 void* __restrict__ o0, void* __restrict__ o1, void* __restrict__ o2)
{
    const int dblk = blockIdx.x;
    const int g = (dblk & 7) * 96 + (dblk >> 3);
    const int ty = g / 12, tx = g - ty * 12;
    const int m0 = ty * 128, n0 = tx * 256;
    const int z = n0 >> 10;
    const int ncol0 = n0 & 1023;
    const float* bias = (z == 0) ? b0 : (z == 1) ? b1 : b2;
    void* out = (z == 0) ? o0 : (z == 1) ? o1 : o2;

    __shared__ unsigned short As[3 * 8192];    // 3 dbuf x [2 half][64][64] = 48 KB
    __shared__ unsigned short Bs[3 * 16384];   // 3 dbuf x [2 half][128][64] = 96 KB
    char* const As_c = (char*)As;
    char* const Bs_c = (char*)Bs;

    const int tid = threadIdx.x;
    const int w = tid >> 6, l = tid & 63;

    // ---- staging geometry: pre-swizzled global src, linear LDS dest ----
    const int trow = tid >> 3;                        // 0..63
    const int tchk = (tid & 7) ^ (trow & 7);          // logical chunk for slot tid&7
    const unsigned short* gA0 = A  + (size_t)(m0 + trow) * C_DIM + tchk * 8;
    const unsigned short* gB0 = Wb + (size_t)(n0 + trow) * C_DIM + tchk * 8;
    const int woff = w * 1024;                        // wave-uniform dest byte

    auto stA = [&](int kt, int h, int ds) {
        gld16(gA0 + (size_t)h * 64 * C_DIM + kt * 64,
              As_c + ds * 16384 + h * 8192 + woff);
    };
    auto stB = [&](int kt, int h, int ds) {
        const unsigned short* p = gB0 + (size_t)h * 128 * C_DIM + kt * 64;
        char* q = Bs_c + ds * 32768 + h * 16384 + woff;
        gld16(p, q);
        gld16(p + (size_t)64 * C_DIM, q + 8192);
    };

    // ---- fragment geometry ----
    const int wr = w >> 2, wc = w & 3;                // 2 x 4 wave grid
    const int lr = l & 15, lkq = l >> 4;
    const int x7 = lr & 7;
    const int ks0b = ((lkq)     ^ x7) * 16;           // chunk bytes, ks=0
    const int ks1b = ((4 + lkq) ^ x7) * 16;           // ks=1
    const int abase = wr * 8192 + lr * 128;           // + i*2048 + ds*16384 + ksb
    const int bbase = (wc >> 1) * 16384 + ((wc & 1) * 64 + lr) * 128;  // + j*2048

    bf16x8 af0, af1, bfr[4];
    f32x4 acc[4][4];
    #pragma unroll
    for (int i = 0; i < 4; ++i)
        #pragma unroll
        for (int j = 0; j < 4; ++j) acc[i][j] = (f32x4){0.f, 0.f, 0.f, 0.f};

    // ---- prologue: tiles 0 -> dbuf0, 1 -> dbuf1 (6 loads each) ----
    stA(0, 0, 0); stA(0, 1, 0); stB(0, 0, 0); stB(0, 1, 0);
    stA(1, 0, 1); stA(1, 1, 1); stB(1, 0, 1); stB(1, 1, 1);
    asm volatile("s_waitcnt vmcnt(6)" ::: "memory");   // tile 0 complete
    __builtin_amdgcn_s_barrier();
    __builtin_amdgcn_sched_barrier(0);

    int d = 0, d2 = 2;   // consume dbuf d; stage into dbuf d2 = (kt+2)%3
    for (int kt = 0; kt < 16; ++kt) {
        const char* Ad = As_c + d * 16384 + abase;
        const char* Bd = Bs_c + d * 32768 + bbase;

        // ================ P0: ks=0, A-rows i=0,1 ================
        af0 = *(const bf16x8*)(Ad + 0 * 2048 + ks0b);
        af1 = *(const bf16x8*)(Ad + 1 * 2048 + ks0b);
        bfr[0] = *(const bf16x8*)(Bd + 0 * 2048 + ks0b);
        bfr[1] = *(const bf16x8*)(Bd + 1 * 2048 + ks0b);
        bfr[2] = *(const bf16x8*)(Bd + 2 * 2048 + ks0b);
        bfr[3] = *(const bf16x8*)(Bd + 3 * 2048 + ks0b);
        if (kt < 14) stA(kt + 2, 0, d2);
        __builtin_amdgcn_sched_barrier(0);
        __builtin_amdgcn_s_barrier();
        asm volatile("s_waitcnt lgkmcnt(0)" ::: "memory");
        __builtin_amdgcn_sched_barrier(0);
        __builtin_amdgcn_s_setprio(1);
        #pragma unroll
        for (int j = 0; j < 4; ++j) {
            acc[0][j] = __builtin_amdgcn_mfma_f32_16x16x32_bf16(af0, bfr[j], acc[0][j], 0, 0, 0);
            acc[1][j] = __builtin_amdgcn_mfma_f32_16x16x32_bf16(af1, bfr[j], acc[1][j], 0, 0, 0);
        }
        __builtin_amdgcn_s_setprio(0);
        __builtin_amdgcn_sched_barrier(0);
        __builtin_amdgcn_s_barrier();

        // ================ P1: ks=0, A-rows i=2,3 ================
        af0 = *(const bf16x8*)(Ad + 2 * 2048 + ks0b);
        af1 = *(const bf16x8*)(Ad + 3 * 2048 + ks0b);
        if (kt < 14) stA(kt + 2, 1, d2);
        __builtin_amdgcn_sched_barrier(0);
        __builtin_amdgcn_s_barrier();
        asm volatile("s_waitcnt lgkmcnt(0)" ::: "memory");
        __builtin_amdgcn_sched_barrier(0);
        __builtin_amdgcn_s_setprio(1);
        #pragma unroll
        for (int j = 0; j < 4; ++j) {
            acc[2][j] = __builtin_amdgcn_mfma_f32_16x16x32_bf16(af0, bfr[j], acc[2][j], 0, 0, 0);
            acc[3][j] = __builtin_amdgcn_mfma_f32_16x16x32_bf16(af1, bfr[j], acc[3][j], 0, 0, 0);
        }
        __builtin_amdgcn_s_setprio(0);
        __builtin_amdgcn_sched_barrier(0);
        __builtin_amdgcn_s_barrier();

        // ================ P2: ks=1, A-rows i=0,1 ================
        af0 = *(const bf16x8*)(Ad + 0 * 2048 + ks1b);
        af1 = *(const bf16x8*)(Ad + 1 * 2048 + ks1b);
        bfr[0] = *(const bf16x8*)(Bd + 0 * 2048 + ks1b);
        bfr[1] = *(const bf16x8*)(Bd + 1 * 2048 + ks1b);
        bfr[2] = *(const bf16x8*)(Bd + 2 * 2048 + ks1b);
        bfr[3] = *(const bf16x8*)(Bd + 3 * 2048 + ks1b);
        if (kt < 14) stB(kt + 2, 0, d2);
        __builtin_amdgcn_sched_barrier(0);
        __builtin_amdgcn_s_barrier();
        asm volatile("s_waitcnt lgkmcnt(0)" ::: "memory");
        __builtin_amdgcn_sched_barrier(0);
        __builtin_amdgcn_s_setprio(1);
        #pragma unroll
        for (int j = 0; j < 4; ++j) {
            acc[0][j] = __builtin_amdgcn_mfma_f32_16x16x32_bf16(af0, bfr[j], acc[0][j], 0, 0, 0);
            acc[1][j] = __builtin_amdgcn_mfma_f32_16x16x32_bf16(af1, bfr[j], acc[1][j], 0, 0, 0);
        }
        __builtin_amdgcn_s_setprio(0);
        __builtin_amdgcn_sched_barrier(0);
        __builtin_amdgcn_s_barrier();

        // ================ P3: ks=1, A-rows i=2,3 ================
        af0 = *(const bf16x8*)(Ad + 2 * 2048 + ks1b);
        af1 = *(const bf16x8*)(Ad + 3 * 2048 + ks1b);
        if (kt < 14) stB(kt + 2, 1, d2);
        // once-per-K-tile counted wait: certifies tile kt+1 before next iter's
        // reads (the barrier below is the cross-wave certification point).
        if (kt < 14)       asm volatile("s_waitcnt vmcnt(6)" ::: "memory");
        else if (kt == 14) asm volatile("s_waitcnt vmcnt(0)" ::: "memory");
        __builtin_amdgcn_sched_barrier(0);
        __builtin_amdgcn_s_barrier();
        asm volatile("s_waitcnt lgkmcnt(0)" ::: "memory");
        __builtin_amdgcn_sched_barrier(0);
        __builtin_amdgcn_s_setprio(1);
        #pragma unroll
        for (int j = 0; j < 4; ++j) {
            acc[2][j] = __builtin_amdgcn_mfma_f32_16x16x32_bf16(af0, bfr[j], acc[2][j], 0, 0, 0);
            acc[3][j] = __builtin_amdgcn_mfma_f32_16x16x32_bf16(af1, bfr[j], acc[3][j], 0, 0, 0);
        }
        __builtin_amdgcn_s_setprio(0);
        __builtin_amdgcn_sched_barrier(0);
        __builtin_amdgcn_s_barrier();

        // rotate ring: (d, d2) for next iter
        const int dn = (d == 2) ? 0 : d + 1;
        d2 = d;          // (kt+1)+2 mod 3 == kt mod 3
        d = dn;
    }

    // ---- epilogue: C/D layout col=lane&15, row=(lane>>4)*4+reg ----
    #pragma unroll
    for (int j = 0; j < 4; ++j) {
        const int col = ncol0 + wc * 64 + j * 16 + lr;
        const float bz = bias[col];
        #pragma unroll
        for (int i = 0; i < 4; ++i) {
            const int rb = m0 + wr * 64 + i * 16 + lkq * 4;
            #pragma unroll
            for (int r = 0; r < 4; ++r) {
                const int row = rb + r;
                float v = acc[i][j][r] + bz;
                if (z == 0) {
                    v = __expf(fminf(fmaxf(v, -60.f), 30.f));
                    ((float*)out)[(size_t)row * C_DIM + col] = v;
                } else if (z == 2) {
                    v = 1.f / (1.f + __expf(-v));
                    ((unsigned short*)out)[(size_t)row * C_DIM + col] = f2bf(v);
                } else {
                    ((unsigned short*)out)[(size_t)row * C_DIM + col] = f2bf(v);
                }
            }
        }
    }
}

// ---------------------------------------------------------------------------
// bf16 MFMA GEMM, BK=64, XOR-swizzled LDS (slot = chunk ^ (row&7)).
// Round-0 proven config: __launch_bounds__(256,2), 32 KiB LDS, VGPR 72.
// mode 3 only: (v+bias)*gamma[t] -> fp32 out.
// Block swizzle: d -> y=((d&7)<<3)|((d>>3)&7), x=d>>6 (XCD L2 locality).
// ---------------------------------------------------------------------------
__global__ __launch_bounds__(256, 2)
void mfma_gemm64(const unsigned short* __restrict__ A,
                 const unsigned short* __restrict__ Wb,
                 const float* __restrict__ b0,
                 void* __restrict__ o0,
                 const float* __restrict__ gamma)
{
    const int d  = blockIdx.x;
    const int y  = ((d & 7) << 3) | ((d >> 3) & 7);
    const int xb = d >> 6;
    const int m0 = y * 128, n0 = xb * 128;

    __shared__ unsigned short As[128 * 64];
    __shared__ unsigned short Bs[128 * 64];

    const int tid = threadIdx.x;
    const int w = tid >> 6, l = tid & 63;

    const int r8  = l >> 3;
    const int c16 = ((l & 7) ^ r8) * 8;
    const unsigned short* gA = A  + (size_t)(m0 + w * 32 + r8) * C_DIM + c16;
    const unsigned short* gB = Wb + (size_t)(n0 + w * 32 + r8) * C_DIM + c16;
    char* lA = (char*)As + (w * 32) * 128;
    char* lB = (char*)Bs + (w * 32) * 128;

    const int wr = w >> 1, wc = w & 1;
    const int lr = l & 15, lkq = l >> 4;
    const int x7 = lr & 7;

    f32x4 acc[4][4];
    #pragma unroll
    for (int i = 0; i < 4; ++i)
        #pragma unroll
        for (int j = 0; j < 4; ++j) acc[i][j] = (f32x4){0.f, 0.f, 0.f, 0.f};

    for (int k0 = 0; k0 < C_DIM; k0 += 64) {
        #pragma unroll
        for (int r = 0; r < 4; ++r) {
            gld16(gA + k0 + (size_t)r * 8 * C_DIM, lA + r * 8 * 128);
            gld16(gB + k0 + (size_t)r * 8 * C_DIM, lB + r * 8 * 128);
        }
        __syncthreads();

        bf16x8 af[2][4], bfv[2][4];
        #pragma unroll
        for (int ks = 0; ks < 2; ++ks) {
            const int slot = ((ks * 4 + lkq) ^ x7) * 8;
            #pragma unroll
            for (int i = 0; i < 4; ++i)
                af[ks][i] = *(const bf16x8*)&As[(wr * 64 + i * 16 + lr) * 64 + slot];
            #pragma unroll
            for (int j = 0; j < 4; ++j)
                bfv[ks][j] = *(const bf16x8*)&Bs[(wc * 64 + j * 16 + lr) * 64 + slot];
        }
        #pragma unroll
        for (int ks = 0; ks < 2; ++ks)
            #pragma unroll
            for (int i = 0; i < 4; ++i)
                #pragma unroll
                for (int j = 0; j < 4; ++j)
                    acc[i][j] = __builtin_amdgcn_mfma_f32_16x16x32_bf16(
                        af[ks][i], bfv[ks][j], acc[i][j], 0, 0, 0);
        __syncthreads();
    }

    #pragma unroll
    for (int j = 0; j < 4; ++j) {
        const int col = n0 + wc * 64 + j * 16 + lr;
        const float bz = b0[col];
        #pragma unroll
        for (int i = 0; i < 4; ++i) {
            const int rb = m0 + wr * 64 + i * 16 + lkq * 4;
            #pragma unroll
            for (int r = 0; r < 4; ++r) {
                const int row = rb + r;
                float v = (acc[i][j][r] + bz) * gamma[row & (T_CTX - 1)];
                ((float*)o0)[(size_t)row * C_DIM + col] = v;
            }
        }
    }
}

// ---------------------------------------------------------------------------
// Chunk-local cumsum of expk + kvT[b,h,c,u] = bf16(expk * v * alpha[h,u]).
// 64-row chunks (q in [0,16)); static u16x8 indexing (rule #20), 8-deep MLP.
// ---------------------------------------------------------------------------
__global__ __launch_bounds__(256)
void cumsum_chunk(const float* __restrict__ expk, const unsigned short* __restrict__ vbf,
                  const float* __restrict__ alpha,
                  float* __restrict__ sumk, unsigned short* __restrict__ kvT,
                  float* __restrict__ aux)
{
    const int n = blockIdx.x * 256 + threadIdx.x;
    const int q = blockIdx.y;
    const int b = blockIdx.z;
    const int h = n >> 6, c = n & 63;
    const size_t base = ((size_t)b * T_CTX + q * 64) * C_DIM + n;
    unsigned short* kvrow = kvT + (((size_t)b * H_NUM + h) * HS + c) * T_CTX + q * 64;
    const float* arow = alpha + h * T_CTX + q * 64;
    float s = 0.f;
    for (int g = 0; g < 8; ++g) {
        u16x8 buf;
        #pragma unroll
        for (int k = 0; k < 8; ++k) {
            const int i = g * 8 + k;
            const size_t idx = base + (size_t)i * C_DIM;
            const float e  = expk[idx];
            const float vv = bf2f(vbf[idx]);
            s += e;
            sumk[idx] = s;
            buf[k] = f2bf(e * vv * arow[i]);
        }
        *(u16x8*)(kvrow + g * 8) = buf;
    }
    aux[((size_t)b * 16 + q) * C_DIM + n] = s;
}

// ---------------------------------------------------------------------------
// wkv via MFMA (Toeplitz):  wkv[t,c] = sum_u twx[1023-t+u] * kvT[c,u]
// 64-row sumk chunks: per-thread chunk index = 2*bx + wr; K/V global loads
// software-pipelined one step ahead of the MFMA cluster.
// ---------------------------------------------------------------------------
#define REPL_STRIDE 1176
#define REPL_USED   1168

__global__ __launch_bounds__(256)
void wkv_mfma(const unsigned short* __restrict__ kvT,
              const float* __restrict__ sumk,
              const unsigned short* __restrict__ sigr,
              const float* __restrict__ tw, const float* __restrict__ beta,
              const float* __restrict__ aux,
              unsigned short* __restrict__ rwkv)
{
    __shared__ unsigned short repl[8 * REPL_STRIDE];
    __shared__ unsigned short kv_s[64 * 72];
    __shared__ unsigned short tw_s[1024];

    const int tid = threadIdx.x;
    const int bx = blockIdx.x;
    const int t0 = bx * 128;
    const int h  = blockIdx.y;
    const int b  = blockIdx.z;

    {
        const int i = tid * 4;
        const float4 v = *(const float4*)(tw + h * T_CTX + i);
        ushort4 o;
        o.x = f2bf(v.x); o.y = f2bf(v.y); o.z = f2bf(v.z); o.w = f2bf(v.w);
        *(ushort4*)&tw_s[i] = o;
    }
    __syncthreads();

    #pragma unroll
    for (int r = 0; r < 8; ++r)
        for (int i = tid; i < REPL_USED; i += 256) {
            const int src = i + r;
            repl[r * REPL_STRIDE + i] = (src < 1024) ? tw_s[src] : (unsigned short)0;
        }
    __syncthreads();

    const int w = tid >> 6, l = tid & 63;
    const int wr = w >> 1, wc = w & 1;
    const int lr = l & 15, lkq = l >> 4;

    const int r    = (7 - lr) & 7;
    const int S0   = 1023 - t0 - wr * 64 - lr + lkq * 8;
    const int abase = 2 * S0 + (2 * REPL_STRIDE - 2) * r;
    const char* repl_c = (const char*)repl;

    const int srow = tid >> 2;
    const int ucol = (tid & 3) * 16;
    const unsigned short* gkv = kvT + (((size_t)b * H_NUM + h) * HS + srow) * T_CTX + ucol;
    unsigned short* skv = &kv_s[srow * 72 + ucol];

    f32x4 acc[4][2];
    #pragma unroll
    for (int i = 0; i < 4; ++i) {
        acc[i][0] = (f32x4){0.f, 0.f, 0.f, 0.f};
        acc[i][1] = (f32x4){0.f, 0.f, 0.f, 0.f};
    }

    const int nsteps = t0 / 64 + 2;
    u16x8 q0 = *(const u16x8*)(gkv);
    u16x8 q1 = *(const u16x8*)(gkv + 8);
    for (int ks = 0; ks < nsteps; ++ks) {
        __syncthreads();
        *(u16x8*)skv       = q0;
        *(u16x8*)(skv + 8) = q1;
        __syncthreads();
        if (ks + 1 < nsteps) {
            const int un = (ks + 1) * 64;
            q0 = *(const u16x8*)(gkv + un);
            q1 = *(const u16x8*)(gkv + un + 8);
        }

        const int ub = abase + 2 * (ks * 64);
        #pragma unroll
        for (int kk = 0; kk < 2; ++kk) {
            bf16x8 af[4], bfv[2];
            #pragma unroll
            for (int i = 0; i < 4; ++i)
                af[i] = *(const bf16x8*)(repl_c + (ub + kk * 64 - i * 32));
            #pragma unroll
            for (int j = 0; j < 2; ++j)
                bfv[j] = *(const bf16x8*)&kv_s[(wc * 32 + j * 16 + lr) * 72 + kk * 32 + lkq * 8];
            #pragma unroll
            for (int i = 0; i < 4; ++i)
                #pragma unroll
                for (int j = 0; j < 2; ++j)
                    acc[i][j] = __builtin_amdgcn_mfma_f32_16x16x32_bf16(
                        af[i], bfv[j], acc[i][j], 0, 0, 0);
        }
    }

    const int cq = 2 * bx + wr;
    float off[2];
    #pragma unroll
    for (int j = 0; j < 2; ++j) {
        const int cl = wc * 32 + j * 16 + lr;
        float o = 0.f;
        for (int q = 0; q < cq; ++q)
            o += aux[((size_t)b * 16 + q) * C_DIM + h * HS + cl];
        off[j] = o;
    }

    #pragma unroll
    for (int i = 0; i < 4; ++i) {
        const int tb = t0 + wr * 64 + i * 16 + lkq * 4;
        #pragma unroll
        for (int rg = 0; rg < 4; ++rg) {
            const int t = tb + rg;
            const float bet = beta[h * T_CTX + t];
            const size_t row_off = ((size_t)(b * T_CTX + t)) * C_DIM + h * HS;
            #pragma unroll
            for (int j = 0; j < 2; ++j) {
                const int cl = wc * 32 + j * 16 + lr;
                const float sk = sumk[row_off + cl] + off[j];
                const float sr = bf2f(sigr[row_off + cl]);
                rwkv[row_off + cl] = f2bf(sr * bet * acc[i][j][rg] / sk);
            }
        }
    }
}

// ---------------------------------------------------------------------------
extern "C" void kernel_launch(void* const* d_in, const int* in_sizes, int n_in,
                              void* d_out, int out_size, void* d_ws, size_t ws_size,
                              hipStream_t stream)
{
    const float* x     = (const float*)d_in[0];
    const float* tw    = (const float*)d_in[1];
    const float* alpha = (const float*)d_in[2];
    const float* beta  = (const float*)d_in[3];
    const float* gamma = (const float*)d_in[4];
    const float* Wk    = (const float*)d_in[5];
    const float* bk    = (const float*)d_in[6];
    const float* Wv    = (const float*)d_in[7];
    const float* bv    = (const float*)d_in[8];
    const float* Wr    = (const float*)d_in[9];
    const float* br    = (const float*)d_in[10];
    const float* Wo    = (const float*)d_in[11];
    const float* bo    = (const float*)d_in[12];
    float* out = (float*)d_out;

    // workspace layout (bytes), max 128M:
    //  [0,32M)   expk fp32    -> rwkv bf16 [0,16M) after cumsum
    //  [32,48M)  v bf16
    //  [48,56M)  weights bf16 (Wk,Wv,Wr,Wo stacked @ 2MB each)
    //  [56,56.5M) aux (raw 64-chunk totals)
    //  [64,96M)  sumk fp32 (chunk-local)  (xs bf16 overlays [64,80M) during proj)
    //  [96,112M) sigr bf16
    //  [112,128M) kvT bf16
    char* W = (char*)d_ws;
    float* expk          = (float*)W;
    unsigned short* rwkv = (unsigned short*)W;
    unsigned short* vbf  = (unsigned short*)(W + (32ull << 20));
    unsigned short* wbf  = (unsigned short*)(W + (48ull << 20));
    float* aux           = (float*)(W + (56ull << 20));
    float* sumk          = (float*)(W + (64ull << 20));
    unsigned short* xs   = (unsigned short*)(W + (64ull << 20));
    unsigned short* sigr = (unsigned short*)(W + (96ull << 20));
    unsigned short* kvT  = (unsigned short*)(W + (112ull << 20));

    const size_t WSZ = (size_t)C_DIM * C_DIM;

    convert_all<<<dim3(12288), 256, 0, stream>>>(x, xs, Wk, Wv, Wr, Wo, wbf);

    // k,v,r projections: N=3072 GEMM, 128x256 pipelined tiles, 768 blocks
    mfma_gemm8p<<<dim3(768), 512, 0, stream>>>(
        xs, wbf, bk, bv, br, expk, vbf, sigr);

    cumsum_chunk<<<dim3(4, 16, 8), 256, 0, stream>>>(expk, vbf, alpha, sumk, kvT, aux);

    wkv_mfma<<<dim3(8, 16, 8), 256, 0, stream>>>(
        kvT, sumk, sigr, tw, beta, aux, rwkv);

    // output projection + gamma (round-0 proven 128^2 kernel)
    mfma_gemm64<<<dim3(512), 256, 0, stream>>>(
        rwkv, wbf + 3 * WSZ, bo, out, gamma);
}

// Round 6
// 264.020 us; speedup vs baseline: 1.0815x; 1.0815x over previous
//
#include <hip/hip_runtime.h>
#include <hip/hip_bf16.h>
#include <cstddef>
#include <cstdint>

#define B_SZ   8
#define T_CTX  1024
#define C_DIM  1024
#define H_NUM  16
#define HS     64
#define M_ROWS (B_SZ * T_CTX)

typedef __attribute__((ext_vector_type(8))) short bf16x8;
typedef __attribute__((ext_vector_type(8))) unsigned short u16x8;
typedef __attribute__((ext_vector_type(4))) float f32x4;

static __device__ inline unsigned short f2bf(float f) {
    __hip_bfloat16 h = __float2bfloat16(f);
    return __builtin_bit_cast(unsigned short, h);
}
static __device__ inline float bf2f(unsigned short u) {
    unsigned int v = ((unsigned int)u) << 16;
    return __builtin_bit_cast(float, v);
}
static __device__ inline void gld16(const void* g, void* l) {
    __builtin_amdgcn_global_load_lds((const __attribute__((address_space(1))) void*)g,
                                     (__attribute__((address_space(3))) void*)l,
                                     16, 0, 0);
}

// ---------------------------------------------------------------------------
// Fused conversion: blocks [0,8192) do x->xs (bf16, time-shifted);
// blocks [8192,12288) do the 4 weight matrices -> stacked bf16.
// ---------------------------------------------------------------------------
__global__ __launch_bounds__(256)
void convert_all(const float* __restrict__ x, unsigned short* __restrict__ xs,
                 const float* __restrict__ Wk, const float* __restrict__ Wv,
                 const float* __restrict__ Wr, const float* __restrict__ Wo,
                 unsigned short* __restrict__ wdst)
{
    const int bid = blockIdx.x;
    if (bid < 8192) {
        const int idx = (bid * 256 + threadIdx.x) * 4;
        const int m = idx >> 10;
        const int c = idx & 1023;
        float4 v;
        if (c < 512) {
            const int t = m & (T_CTX - 1);
            if (t == 0) v = make_float4(0.f, 0.f, 0.f, 0.f);
            else        v = *(const float4*)(x + (size_t)(m - 1) * C_DIM + c);
        } else {
            v = *(const float4*)(x + idx);
        }
        ushort4 o;
        o.x = f2bf(v.x); o.y = f2bf(v.y); o.z = f2bf(v.z); o.w = f2bf(v.w);
        *(ushort4*)(xs + idx) = o;
    } else {
        const int wid = bid - 8192;
        const int z = wid >> 10;
        const float* src = (z == 0) ? Wk : (z == 1) ? Wv : (z == 2) ? Wr : Wo;
        const int idx = ((wid & 1023) * 256 + threadIdx.x) * 4;
        const float4 v = *(const float4*)(src + idx);
        ushort4 o;
        o.x = f2bf(v.x); o.y = f2bf(v.y); o.z = f2bf(v.z); o.w = f2bf(v.w);
        *(ushort4*)(wdst + (size_t)z * (C_DIM * C_DIM) + idx) = o;
    }
}

// ---------------------------------------------------------------------------
// bf16 MFMA GEMM, BK=64, XOR-swizzled LDS (slot = chunk ^ (row&7)) to break
// the 16-way bank conflict of 128B-row fragment reads down to the b128
// 8-lane minimum.  Staging keeps gld16-contiguous writes; the lane->global
// chunk mapping carries the permutation.
// ROUND-0 PROVEN CONFIG: __launch_bounds__(256,2), 32 KiB LDS, VGPR 72,
// 75.4 us / 683 TF on the big GEMM.  (256,4), 3-ring and 8-phase variants
// all regressed (rounds 1-5) — the sync structure stays EXACTLY as-is.
// multi=1: W stacked [3072x1024]; mode = n0>>10:
//   0: exp(clip)->fp32 expk ; 1: identity->bf16 v ; 2: sigmoid->bf16 sigr
// multi=0: mode 3: (v+bias)*gamma[t] -> fp32 out
// Block swizzle: d -> y=((d&7)<<3)|((d>>3)&7), x=d>>6 (XCD L2 locality).
// ---------------------------------------------------------------------------
__global__ __launch_bounds__(256, 2)
void mfma_gemm64(const unsigned short* __restrict__ A,
                 const unsigned short* __restrict__ Wb,
                 const float* __restrict__ b0, const float* __restrict__ b1,
                 const float* __restrict__ b2,
                 void* __restrict__ o0, void* __restrict__ o1, void* __restrict__ o2,
                 const float* __restrict__ gamma, int multi)
{
    const int d  = blockIdx.x;
    const int y  = ((d & 7) << 3) | ((d >> 3) & 7);
    const int xb = d >> 6;
    const int m0 = y * 128, n0 = xb * 128;

    int mode, ncol0;
    const float* bias;
    void* out;
    if (multi) {
        const int z = n0 >> 10;
        mode = z;
        ncol0 = n0 & 1023;
        bias = (z == 0) ? b0 : (z == 1) ? b1 : b2;
        out  = (z == 0) ? o0 : (z == 1) ? o1 : o2;
    } else {
        mode = 3; ncol0 = n0; bias = b0; out = o0;
    }

    __shared__ unsigned short As[128 * 64];
    __shared__ unsigned short Bs[128 * 64];

    const int tid = threadIdx.x;
    const int w = tid >> 6, l = tid & 63;

    // staging: wave w covers rows [w*32, w*32+32) in 4 rounds of 8 rows.
    // lane l -> row offset r8 = l>>3, fetches global k-chunk (l&7)^r8 so the
    // contiguous LDS write leaves slot s of row R holding chunk s^(R&7).
    const int r8  = l >> 3;
    const int c16 = ((l & 7) ^ r8) * 8;
    const unsigned short* gA = A  + (size_t)(m0 + w * 32 + r8) * C_DIM + c16;
    const unsigned short* gB = Wb + (size_t)(n0 + w * 32 + r8) * C_DIM + c16;
    char* lA = (char*)As + (w * 32) * 128;
    char* lB = (char*)Bs + (w * 32) * 128;

    const int wr = w >> 1, wc = w & 1;
    const int lr = l & 15, lkq = l >> 4;
    const int x7 = lr & 7;

    f32x4 acc[4][4];
    #pragma unroll
    for (int i = 0; i < 4; ++i)
        #pragma unroll
        for (int j = 0; j < 4; ++j) acc[i][j] = (f32x4){0.f, 0.f, 0.f, 0.f};

    for (int k0 = 0; k0 < C_DIM; k0 += 64) {
        #pragma unroll
        for (int r = 0; r < 4; ++r) {
            gld16(gA + k0 + (size_t)r * 8 * C_DIM, lA + r * 8 * 128);
            gld16(gB + k0 + (size_t)r * 8 * C_DIM, lB + r * 8 * 128);
        }
        __syncthreads();

        bf16x8 af[2][4], bfv[2][4];
        #pragma unroll
        for (int ks = 0; ks < 2; ++ks) {
            const int slot = ((ks * 4 + lkq) ^ x7) * 8;   // swizzled k-offset
            #pragma unroll
            for (int i = 0; i < 4; ++i)
                af[ks][i] = *(const bf16x8*)&As[(wr * 64 + i * 16 + lr) * 64 + slot];
            #pragma unroll
            for (int j = 0; j < 4; ++j)
                bfv[ks][j] = *(const bf16x8*)&Bs[(wc * 64 + j * 16 + lr) * 64 + slot];
        }
        #pragma unroll
        for (int ks = 0; ks < 2; ++ks)
            #pragma unroll
            for (int i = 0; i < 4; ++i)
                #pragma unroll
                for (int j = 0; j < 4; ++j)
                    acc[i][j] = __builtin_amdgcn_mfma_f32_16x16x32_bf16(
                        af[ks][i], bfv[ks][j], acc[i][j], 0, 0, 0);
        __syncthreads();
    }

    // epilogue: C/D layout col=lane&15, row=(lane>>4)*4+reg
    #pragma unroll
    for (int j = 0; j < 4; ++j) {
        const int col = ncol0 + wc * 64 + j * 16 + lr;
        const float bz = bias[col];
        #pragma unroll
        for (int i = 0; i < 4; ++i) {
            const int rb = m0 + wr * 64 + i * 16 + lkq * 4;
            #pragma unroll
            for (int r = 0; r < 4; ++r) {
                const int row = rb + r;
                float v = acc[i][j][r] + bz;
                if (mode == 0)      v = __expf(fminf(fmaxf(v, -60.f), 30.f));
                else if (mode == 2) v = 1.f / (1.f + __expf(-v));
                else if (mode == 3) v *= gamma[row & (T_CTX - 1)];
                if (mode == 1 || mode == 2)
                    ((unsigned short*)out)[(size_t)row * C_DIM + col] = f2bf(v);
                else
                    ((float*)out)[(size_t)row * C_DIM + col] = v;
            }
        }
    }
}

// ---------------------------------------------------------------------------
// Chunk-local cumsum of expk + kvT[b,h,c,u] = bf16(expk * v * alpha[h,u]).
// 64-row chunks (q in [0,16)); static u16x8 indexing (rule #20), 8-deep MLP.
// NEW: kvT stores are transposed through LDS. Previously each lane scattered
// 16B to 2KB-strided rows (64 partial granules per wave-store). Now wave w
// (= one head h, c = lane) stages its [64c][64u] bf16 tile in LDS (stride 68
// -> <=4-way bank aliasing) and writes out 8 rows x 128B contiguous,
// granule-aligned segments per iteration.
// sumk holds CHUNK-LOCAL prefix sums; aux[b,q,n] = raw 64-chunk totals.
// ---------------------------------------------------------------------------
__global__ __launch_bounds__(256)
void cumsum_chunk(const float* __restrict__ expk, const unsigned short* __restrict__ vbf,
                  const float* __restrict__ alpha,
                  float* __restrict__ sumk, unsigned short* __restrict__ kvT,
                  float* __restrict__ aux)
{
    __shared__ unsigned short kvs[4][64 * 68];
    const int tid = threadIdx.x;
    const int w = tid >> 6, l = tid & 63;
    const int n = blockIdx.x * 256 + tid;    // channel; c = n&63 = l
    const int q = blockIdx.y;                // 16 chunks of 64 rows
    const int b = blockIdx.z;
    const int h = n >> 6;                    // = blockIdx.x*4 + w (wave-uniform)
    const size_t base = ((size_t)b * T_CTX + q * 64) * C_DIM + n;
    const float* arow = alpha + h * T_CTX + q * 64;

    float s = 0.f;
    for (int g = 0; g < 8; ++g) {
        u16x8 buf;
        #pragma unroll
        for (int k = 0; k < 8; ++k) {
            const int i = g * 8 + k;
            const size_t idx = base + (size_t)i * C_DIM;
            const float e  = expk[idx];
            const float vv = bf2f(vbf[idx]);
            s += e;
            sumk[idx] = s;
            buf[k] = f2bf(e * vv * arow[i]);
        }
        *(u16x8*)&kvs[w][l * 68 + g * 8] = buf;
    }
    aux[((size_t)b * 16 + q) * C_DIM + n] = s;

    __syncthreads();

    // transposed write-out: lane l covers row c2=(l>>3)+r*8, u-slice (l&7)*8.
    // lanes 0..7 write 8x16B = one contiguous 128B run of row r*8, etc.
    const int u8 = (l & 7) * 8;
    #pragma unroll
    for (int r = 0; r < 8; ++r) {
        const int c2 = (l >> 3) + r * 8;
        const u16x8 v = *(const u16x8*)&kvs[w][c2 * 68 + u8];
        *(u16x8*)(kvT + (((size_t)b * H_NUM + h) * HS + c2) * T_CTX + q * 64 + u8) = v;
    }
}

// ---------------------------------------------------------------------------
// wkv via MFMA (Toeplitz):  wkv[t,c] = sum_u twx[1023-t+u] * kvT[c,u]
// A-frags from 8 shift-replicas of twx in LDS; B = kvT tile in padded LDS.
// Epilogue: rwkv = sigr * beta[t] * acc / (sumk_chunk + prefix(aux))  (bf16)
// 64-row sumk chunks: per-thread chunk index = 2*bx + wr; K/V global loads
// software-pipelined one step ahead of the MFMA cluster.
// ---------------------------------------------------------------------------
#define REPL_STRIDE 1176
#define REPL_USED   1168

__global__ __launch_bounds__(256)
void wkv_mfma(const unsigned short* __restrict__ kvT,
              const float* __restrict__ sumk,
              const unsigned short* __restrict__ sigr,
              const float* __restrict__ tw, const float* __restrict__ beta,
              const float* __restrict__ aux,
              unsigned short* __restrict__ rwkv)
{
    __shared__ unsigned short repl[8 * REPL_STRIDE];
    __shared__ unsigned short kv_s[64 * 72];
    __shared__ unsigned short tw_s[1024];

    const int tid = threadIdx.x;
    const int bx = blockIdx.x;
    const int t0 = bx * 128;
    const int h  = blockIdx.y;
    const int b  = blockIdx.z;

    {
        const int i = tid * 4;
        const float4 v = *(const float4*)(tw + h * T_CTX + i);
        ushort4 o;
        o.x = f2bf(v.x); o.y = f2bf(v.y); o.z = f2bf(v.z); o.w = f2bf(v.w);
        *(ushort4*)&tw_s[i] = o;
    }
    __syncthreads();

    #pragma unroll
    for (int r = 0; r < 8; ++r)
        for (int i = tid; i < REPL_USED; i += 256) {
            const int src = i + r;
            repl[r * REPL_STRIDE + i] = (src < 1024) ? tw_s[src] : (unsigned short)0;
        }
    __syncthreads();

    const int w = tid >> 6, l = tid & 63;
    const int wr = w >> 1, wc = w & 1;
    const int lr = l & 15, lkq = l >> 4;

    const int r    = (7 - lr) & 7;
    const int S0   = 1023 - t0 - wr * 64 - lr + lkq * 8;
    const int abase = 2 * S0 + (2 * REPL_STRIDE - 2) * r;
    const char* repl_c = (const char*)repl;

    const int srow = tid >> 2;
    const int ucol = (tid & 3) * 16;
    const unsigned short* gkv = kvT + (((size_t)b * H_NUM + h) * HS + srow) * T_CTX + ucol;
    unsigned short* skv = &kv_s[srow * 72 + ucol];

    f32x4 acc[4][2];
    #pragma unroll
    for (int i = 0; i < 4; ++i) {
        acc[i][0] = (f32x4){0.f, 0.f, 0.f, 0.f};
        acc[i][1] = (f32x4){0.f, 0.f, 0.f, 0.f};
    }

    const int nsteps = t0 / 64 + 2;
    u16x8 q0 = *(const u16x8*)(gkv);
    u16x8 q1 = *(const u16x8*)(gkv + 8);
    for (int ks = 0; ks < nsteps; ++ks) {
        __syncthreads();
        *(u16x8*)skv       = q0;
        *(u16x8*)(skv + 8) = q1;
        __syncthreads();
        if (ks + 1 < nsteps) {
            const int un = (ks + 1) * 64;
            q0 = *(const u16x8*)(gkv + un);
            q1 = *(const u16x8*)(gkv + un + 8);
        }

        const int ub = abase + 2 * (ks * 64);
        #pragma unroll
        for (int kk = 0; kk < 2; ++kk) {
            bf16x8 af[4], bfv[2];
            #pragma unroll
            for (int i = 0; i < 4; ++i)
                af[i] = *(const bf16x8*)(repl_c + (ub + kk * 64 - i * 32));
            #pragma unroll
            for (int j = 0; j < 2; ++j)
                bfv[j] = *(const bf16x8*)&kv_s[(wc * 32 + j * 16 + lr) * 72 + kk * 32 + lkq * 8];
            #pragma unroll
            for (int i = 0; i < 4; ++i)
                #pragma unroll
                for (int j = 0; j < 2; ++j)
                    acc[i][j] = __builtin_amdgcn_mfma_f32_16x16x32_bf16(
                        af[i], bfv[j], acc[i][j], 0, 0, 0);
        }
    }

    const int cq = 2 * bx + wr;
    float off[2];
    #pragma unroll
    for (int j = 0; j < 2; ++j) {
        const int cl = wc * 32 + j * 16 + lr;
        float o = 0.f;
        for (int q = 0; q < cq; ++q)
            o += aux[((size_t)b * 16 + q) * C_DIM + h * HS + cl];
        off[j] = o;
    }

    #pragma unroll
    for (int i = 0; i < 4; ++i) {
        const int tb = t0 + wr * 64 + i * 16 + lkq * 4;
        #pragma unroll
        for (int rg = 0; rg < 4; ++rg) {
            const int t = tb + rg;
            const float bet = beta[h * T_CTX + t];
            const size_t row_off = ((size_t)(b * T_CTX + t)) * C_DIM + h * HS;
            #pragma unroll
            for (int j = 0; j < 2; ++j) {
                const int cl = wc * 32 + j * 16 + lr;
                const float sk = sumk[row_off + cl] + off[j];
                const float sr = bf2f(sigr[row_off + cl]);
                rwkv[row_off + cl] = f2bf(sr * bet * acc[i][j][rg] / sk);
            }
        }
    }
}

// ---------------------------------------------------------------------------
extern "C" void kernel_launch(void* const* d_in, const int* in_sizes, int n_in,
                              void* d_out, int out_size, void* d_ws, size_t ws_size,
                              hipStream_t stream)
{
    const float* x     = (const float*)d_in[0];
    const float* tw    = (const float*)d_in[1];
    const float* alpha = (const float*)d_in[2];
    const float* beta  = (const float*)d_in[3];
    const float* gamma = (const float*)d_in[4];
    const float* Wk    = (const float*)d_in[5];
    const float* bk    = (const float*)d_in[6];
    const float* Wv    = (const float*)d_in[7];
    const float* bv    = (const float*)d_in[8];
    const float* Wr    = (const float*)d_in[9];
    const float* br    = (const float*)d_in[10];
    const float* Wo    = (const float*)d_in[11];
    const float* bo    = (const float*)d_in[12];
    float* out = (float*)d_out;

    // workspace layout (bytes), max 128M:
    //  [0,32M)   expk fp32    -> rwkv bf16 [0,16M) after cumsum
    //  [32,48M)  v bf16
    //  [48,56M)  weights bf16 (Wk,Wv,Wr,Wo stacked @ 2MB each)
    //  [56,56.5M) aux (raw 64-chunk totals)
    //  [64,96M)  sumk fp32 (chunk-local)  (xs bf16 overlays [64,80M) during proj)
    //  [96,112M) sigr bf16
    //  [112,128M) kvT bf16
    char* W = (char*)d_ws;
    float* expk          = (float*)W;
    unsigned short* rwkv = (unsigned short*)W;
    unsigned short* vbf  = (unsigned short*)(W + (32ull << 20));
    unsigned short* wbf  = (unsigned short*)(W + (48ull << 20));
    float* aux           = (float*)(W + (56ull << 20));
    float* sumk          = (float*)(W + (64ull << 20));
    unsigned short* xs   = (unsigned short*)(W + (64ull << 20));
    unsigned short* sigr = (unsigned short*)(W + (96ull << 20));
    unsigned short* kvT  = (unsigned short*)(W + (112ull << 20));

    const size_t WSZ = (size_t)C_DIM * C_DIM;

    convert_all<<<dim3(12288), 256, 0, stream>>>(x, xs, Wk, Wv, Wr, Wo, wbf);

    // k,v,r projections as one N=3072 GEMM (W stacked), XCD-swizzled
    mfma_gemm64<<<dim3(1536), 256, 0, stream>>>(
        xs, wbf, bk, bv, br, expk, vbf, sigr, gamma, 1);

    cumsum_chunk<<<dim3(4, 16, 8), 256, 0, stream>>>(expk, vbf, alpha, sumk, kvT, aux);

    wkv_mfma<<<dim3(8, 16, 8), 256, 0, stream>>>(
        kvT, sumk, sigr, tw, beta, aux, rwkv);

    // output projection + gamma
    mfma_gemm64<<<dim3(512), 256, 0, stream>>>(
        rwkv, wbf + 3 * WSZ, bo, nullptr, nullptr,
        out, nullptr, nullptr, gamma, 0);
}

// Round 7
// 259.493 us; speedup vs baseline: 1.1004x; 1.0174x over previous
//
#include <hip/hip_runtime.h>
#include <hip/hip_bf16.h>
#include <cstddef>
#include <cstdint>

#define B_SZ   8
#define T_CTX  1024
#define C_DIM  1024
#define H_NUM  16
#define HS     64
#define M_ROWS (B_SZ * T_CTX)

typedef __attribute__((ext_vector_type(8))) short bf16x8;
typedef __attribute__((ext_vector_type(8))) unsigned short u16x8;
typedef __attribute__((ext_vector_type(4))) float f32x4;

static __device__ inline unsigned short f2bf(float f) {
    __hip_bfloat16 h = __float2bfloat16(f);
    return __builtin_bit_cast(unsigned short, h);
}
static __device__ inline float bf2f(unsigned short u) {
    unsigned int v = ((unsigned int)u) << 16;
    return __builtin_bit_cast(float, v);
}
static __device__ inline void gld16(const void* g, void* l) {
    __builtin_amdgcn_global_load_lds((const __attribute__((address_space(1))) void*)g,
                                     (__attribute__((address_space(3))) void*)l,
                                     16, 0, 0);
}

// ---------------------------------------------------------------------------
// Fused conversion: blocks [0,8192) do x->xs (bf16, time-shifted);
// blocks [8192,12288) do the 4 weight matrices -> stacked bf16.
// ---------------------------------------------------------------------------
__global__ __launch_bounds__(256)
void convert_all(const float* __restrict__ x, unsigned short* __restrict__ xs,
                 const float* __restrict__ Wk, const float* __restrict__ Wv,
                 const float* __restrict__ Wr, const float* __restrict__ Wo,
                 unsigned short* __restrict__ wdst)
{
    const int bid = blockIdx.x;
    if (bid < 8192) {
        const int idx = (bid * 256 + threadIdx.x) * 4;
        const int m = idx >> 10;
        const int c = idx & 1023;
        float4 v;
        if (c < 512) {
            const int t = m & (T_CTX - 1);
            if (t == 0) v = make_float4(0.f, 0.f, 0.f, 0.f);
            else        v = *(const float4*)(x + (size_t)(m - 1) * C_DIM + c);
        } else {
            v = *(const float4*)(x + idx);
        }
        ushort4 o;
        o.x = f2bf(v.x); o.y = f2bf(v.y); o.z = f2bf(v.z); o.w = f2bf(v.w);
        *(ushort4*)(xs + idx) = o;
    } else {
        const int wid = bid - 8192;
        const int z = wid >> 10;
        const float* src = (z == 0) ? Wk : (z == 1) ? Wv : (z == 2) ? Wr : Wo;
        const int idx = ((wid & 1023) * 256 + threadIdx.x) * 4;
        const float4 v = *(const float4*)(src + idx);
        ushort4 o;
        o.x = f2bf(v.x); o.y = f2bf(v.y); o.z = f2bf(v.z); o.w = f2bf(v.w);
        *(ushort4*)(wdst + (size_t)z * (C_DIM * C_DIM) + idx) = o;
    }
}

// ---------------------------------------------------------------------------
// bf16 MFMA GEMM, BK=64, XOR-swizzled LDS (slot = chunk ^ (row&7)).
// ROUND-0 PROVEN CONFIG: __launch_bounds__(256,2), 32 KiB LDS, VGPR ~72.
// (256,4), 3-ring and 8-phase variants all regressed (rounds 1-5) — the
// sync structure is frozen.
// NEW (r7): bf16 modes (1,2) write through an LDS-transposed epilogue.
// Old path stored 16lane x 2B = 32B partial-granule segments -> ~2x write
// amplification (WRITE_SIZE 100MB vs 64 ideal). Now: stage the 128x128 bf16
// tile into the (dead) As/Bs buffer with a (row&7)<<5 XOR swizzle (2-way
// write aliasing = free), then write 256B-contiguous full rows.
// multi=1: W stacked [3072x1024]; mode = n0>>10:
//   0: exp(clip)->fp32 expk ; 1: identity->bf16 v ; 2: sigmoid->bf16 sigr
// multi=0: mode 3: (v+bias)*gamma[t] -> fp32 out (64B segments, unchanged)
// Block swizzle: d -> y=((d&7)<<3)|((d>>3)&7), x=d>>6 (XCD L2 locality).
// ---------------------------------------------------------------------------
__global__ __launch_bounds__(256, 2)
void mfma_gemm64(const unsigned short* __restrict__ A,
                 const unsigned short* __restrict__ Wb,
                 const float* __restrict__ b0, const float* __restrict__ b1,
                 const float* __restrict__ b2,
                 void* __restrict__ o0, void* __restrict__ o1, void* __restrict__ o2,
                 const float* __restrict__ gamma, int multi)
{
    const int d  = blockIdx.x;
    const int y  = ((d & 7) << 3) | ((d >> 3) & 7);
    const int xb = d >> 6;
    const int m0 = y * 128, n0 = xb * 128;

    int mode, ncol0;
    const float* bias;
    void* out;
    if (multi) {
        const int z = n0 >> 10;
        mode = z;
        ncol0 = n0 & 1023;
        bias = (z == 0) ? b0 : (z == 1) ? b1 : b2;
        out  = (z == 0) ? o0 : (z == 1) ? o1 : o2;
    } else {
        mode = 3; ncol0 = n0; bias = b0; out = o0;
    }

    // single 32KB buffer: [0,8192) = A-tile, [8192,16384) = B-tile;
    // whole buffer reused as the bf16 C-staging area in the epilogue.
    __shared__ unsigned short Sh[2 * 128 * 64];

    const int tid = threadIdx.x;
    const int w = tid >> 6, l = tid & 63;

    // staging: wave w covers rows [w*32, w*32+32) in 4 rounds of 8 rows.
    // lane l -> row offset r8 = l>>3, fetches global k-chunk (l&7)^r8 so the
    // contiguous LDS write leaves slot s of row R holding chunk s^(R&7).
    const int r8  = l >> 3;
    const int c16 = ((l & 7) ^ r8) * 8;
    const unsigned short* gA = A  + (size_t)(m0 + w * 32 + r8) * C_DIM + c16;
    const unsigned short* gB = Wb + (size_t)(n0 + w * 32 + r8) * C_DIM + c16;
    char* lA = (char*)Sh + (w * 32) * 128;
    char* lB = (char*)Sh + 16384 + (w * 32) * 128;

    const int wr = w >> 1, wc = w & 1;
    const int lr = l & 15, lkq = l >> 4;
    const int x7 = lr & 7;

    f32x4 acc[4][4];
    #pragma unroll
    for (int i = 0; i < 4; ++i)
        #pragma unroll
        for (int j = 0; j < 4; ++j) acc[i][j] = (f32x4){0.f, 0.f, 0.f, 0.f};

    for (int k0 = 0; k0 < C_DIM; k0 += 64) {
        #pragma unroll
        for (int r = 0; r < 4; ++r) {
            gld16(gA + k0 + (size_t)r * 8 * C_DIM, lA + r * 8 * 128);
            gld16(gB + k0 + (size_t)r * 8 * C_DIM, lB + r * 8 * 128);
        }
        __syncthreads();

        bf16x8 af[2][4], bfv[2][4];
        #pragma unroll
        for (int ks = 0; ks < 2; ++ks) {
            const int slot = ((ks * 4 + lkq) ^ x7) * 8;   // swizzled k-offset
            #pragma unroll
            for (int i = 0; i < 4; ++i)
                af[ks][i] = *(const bf16x8*)&Sh[(wr * 64 + i * 16 + lr) * 64 + slot];
            #pragma unroll
            for (int j = 0; j < 4; ++j)
                bfv[ks][j] = *(const bf16x8*)&Sh[8192 + (wc * 64 + j * 16 + lr) * 64 + slot];
        }
        #pragma unroll
        for (int ks = 0; ks < 2; ++ks)
            #pragma unroll
            for (int i = 0; i < 4; ++i)
                #pragma unroll
                for (int j = 0; j < 4; ++j)
                    acc[i][j] = __builtin_amdgcn_mfma_f32_16x16x32_bf16(
                        af[ks][i], bfv[ks][j], acc[i][j], 0, 0, 0);
        __syncthreads();
    }

    // epilogue: C/D layout col=lane&15, row=(lane>>4)*4+reg
    if (mode == 1 || mode == 2) {
        // ---- bf16 modes: LDS-transposed coalesced stores ----
        char* const Cs = (char*)Sh;   // 32KB, dead after final K-loop barrier
        #pragma unroll
        for (int j = 0; j < 4; ++j) {
            const int col_l = wc * 64 + j * 16 + lr;
            const float bz = bias[ncol0 + col_l];
            #pragma unroll
            for (int i = 0; i < 4; ++i) {
                const int rbl = wr * 64 + i * 16 + lkq * 4;
                #pragma unroll
                for (int r = 0; r < 4; ++r) {
                    const int row_l = rbl + r;
                    float v = acc[i][j][r] + bz;
                    if (mode == 2) v = 1.f / (1.f + __expf(-v));
                    const int byte = row_l * 256 + ((col_l * 2) ^ ((row_l & 7) << 5));
                    *(unsigned short*)(Cs + byte) = f2bf(v);
                }
            }
        }
        __syncthreads();
        // 16 lanes x 16B = 256B contiguous per output row; 8 rounds x 16 rows
        #pragma unroll
        for (int it = 0; it < 8; ++it) {
            const int row_l = (tid >> 4) + it * 16;
            const int k = tid & 15;
            const int byte = row_l * 256 + ((k * 16) ^ ((row_l & 7) << 5));
            const u16x8 v = *(const u16x8*)(Cs + byte);
            *(u16x8*)((unsigned short*)out + (size_t)(m0 + row_l) * C_DIM + ncol0 + k * 8) = v;
        }
    } else {
        // ---- fp32 modes (0,3): original path (64B segments, no amplification)
        #pragma unroll
        for (int j = 0; j < 4; ++j) {
            const int col = ncol0 + wc * 64 + j * 16 + lr;
            const float bz = bias[col];
            #pragma unroll
            for (int i = 0; i < 4; ++i) {
                const int rb = m0 + wr * 64 + i * 16 + lkq * 4;
                #pragma unroll
                for (int r = 0; r < 4; ++r) {
                    const int row = rb + r;
                    float v = acc[i][j][r] + bz;
                    if (mode == 0)      v = __expf(fminf(fmaxf(v, -60.f), 30.f));
                    else                v *= gamma[row & (T_CTX - 1)];
                    ((float*)out)[(size_t)row * C_DIM + col] = v;
                }
            }
        }
    }
}

// ---------------------------------------------------------------------------
// Chunk-local cumsum of expk + kvT[b,h,c,u] = bf16(expk * v * alpha[h,u]).
// 64-row chunks (q in [0,16)); static u16x8 indexing (rule #20), 8-deep MLP.
// kvT stores transposed through LDS (r6 win): wave stages [64c][64u] tile
// (stride 68 -> <=4-way aliasing), writes 8x128B contiguous runs.
// sumk holds CHUNK-LOCAL prefix sums; aux[b,q,n] = raw 64-chunk totals.
// ---------------------------------------------------------------------------
__global__ __launch_bounds__(256)
void cumsum_chunk(const float* __restrict__ expk, const unsigned short* __restrict__ vbf,
                  const float* __restrict__ alpha,
                  float* __restrict__ sumk, unsigned short* __restrict__ kvT,
                  float* __restrict__ aux)
{
    __shared__ unsigned short kvs[4][64 * 68];
    const int tid = threadIdx.x;
    const int w = tid >> 6, l = tid & 63;
    const int n = blockIdx.x * 256 + tid;    // channel; c = n&63 = l
    const int q = blockIdx.y;                // 16 chunks of 64 rows
    const int b = blockIdx.z;
    const int h = n >> 6;                    // = blockIdx.x*4 + w (wave-uniform)
    const size_t base = ((size_t)b * T_CTX + q * 64) * C_DIM + n;
    const float* arow = alpha + h * T_CTX + q * 64;

    float s = 0.f;
    for (int g = 0; g < 8; ++g) {
        u16x8 buf;
        #pragma unroll
        for (int k = 0; k < 8; ++k) {
            const int i = g * 8 + k;
            const size_t idx = base + (size_t)i * C_DIM;
            const float e  = expk[idx];
            const float vv = bf2f(vbf[idx]);
            s += e;
            sumk[idx] = s;
            buf[k] = f2bf(e * vv * arow[i]);
        }
        *(u16x8*)&kvs[w][l * 68 + g * 8] = buf;
    }
    aux[((size_t)b * 16 + q) * C_DIM + n] = s;

    __syncthreads();

    // transposed write-out: lane l covers row c2=(l>>3)+r*8, u-slice (l&7)*8.
    const int u8 = (l & 7) * 8;
    #pragma unroll
    for (int r = 0; r < 8; ++r) {
        const int c2 = (l >> 3) + r * 8;
        const u16x8 v = *(const u16x8*)&kvs[w][c2 * 68 + u8];
        *(u16x8*)(kvT + (((size_t)b * H_NUM + h) * HS + c2) * T_CTX + q * 64 + u8) = v;
    }
}

// ---------------------------------------------------------------------------
// wkv via MFMA (Toeplitz):  wkv[t,c] = sum_u twx[1023-t+u] * kvT[c,u]
// A-frags from 8 shift-replicas of twx in LDS; B = kvT tile in padded LDS.
// Epilogue: rwkv = sigr * beta[t] * acc / (sumk_chunk + prefix(aux))  (bf16)
// 64-row sumk chunks: per-thread chunk index = 2*bx + wr; K/V global loads
// software-pipelined one step ahead of the MFMA cluster.
// NEW (r7): rwkv stores go through an LDS-transposed staging buffer aliased
// over the dead repl region (18.8KB >= 16KB needed): old path wrote 32B
// partial-granule segments (2x amplification on 16MB); now 128B runs.
// ---------------------------------------------------------------------------
#define REPL_STRIDE 1176
#define REPL_USED   1168

__global__ __launch_bounds__(256)
void wkv_mfma(const unsigned short* __restrict__ kvT,
              const float* __restrict__ sumk,
              const unsigned short* __restrict__ sigr,
              const float* __restrict__ tw, const float* __restrict__ beta,
              const float* __restrict__ aux,
              unsigned short* __restrict__ rwkv)
{
    __shared__ unsigned short repl[8 * REPL_STRIDE];
    __shared__ unsigned short kv_s[64 * 72];
    __shared__ unsigned short tw_s[1024];

    const int tid = threadIdx.x;
    const int bx = blockIdx.x;
    const int t0 = bx * 128;
    const int h  = blockIdx.y;
    const int b  = blockIdx.z;

    {
        const int i = tid * 4;
        const float4 v = *(const float4*)(tw + h * T_CTX + i);
        ushort4 o;
        o.x = f2bf(v.x); o.y = f2bf(v.y); o.z = f2bf(v.z); o.w = f2bf(v.w);
        *(ushort4*)&tw_s[i] = o;
    }
    __syncthreads();

    #pragma unroll
    for (int r = 0; r < 8; ++r)
        for (int i = tid; i < REPL_USED; i += 256) {
            const int src = i + r;
            repl[r * REPL_STRIDE + i] = (src < 1024) ? tw_s[src] : (unsigned short)0;
        }
    __syncthreads();

    const int w = tid >> 6, l = tid & 63;
    const int wr = w >> 1, wc = w & 1;
    const int lr = l & 15, lkq = l >> 4;

    const int r    = (7 - lr) & 7;
    const int S0   = 1023 - t0 - wr * 64 - lr + lkq * 8;
    const int abase = 2 * S0 + (2 * REPL_STRIDE - 2) * r;
    const char* repl_c = (const char*)repl;

    const int srow = tid >> 2;
    const int ucol = (tid & 3) * 16;
    const unsigned short* gkv = kvT + (((size_t)b * H_NUM + h) * HS + srow) * T_CTX + ucol;
    unsigned short* skv = &kv_s[srow * 72 + ucol];

    f32x4 acc[4][2];
    #pragma unroll
    for (int i = 0; i < 4; ++i) {
        acc[i][0] = (f32x4){0.f, 0.f, 0.f, 0.f};
        acc[i][1] = (f32x4){0.f, 0.f, 0.f, 0.f};
    }

    const int nsteps = t0 / 64 + 2;
    u16x8 q0 = *(const u16x8*)(gkv);
    u16x8 q1 = *(const u16x8*)(gkv + 8);
    for (int ks = 0; ks < nsteps; ++ks) {
        __syncthreads();
        *(u16x8*)skv       = q0;
        *(u16x8*)(skv + 8) = q1;
        __syncthreads();
        if (ks + 1 < nsteps) {
            const int un = (ks + 1) * 64;
            q0 = *(const u16x8*)(gkv + un);
            q1 = *(const u16x8*)(gkv + un + 8);
        }

        const int ub = abase + 2 * (ks * 64);
        #pragma unroll
        for (int kk = 0; kk < 2; ++kk) {
            bf16x8 af[4], bfv[2];
            #pragma unroll
            for (int i = 0; i < 4; ++i)
                af[i] = *(const bf16x8*)(repl_c + (ub + kk * 64 - i * 32));
            #pragma unroll
            for (int j = 0; j < 2; ++j)
                bfv[j] = *(const bf16x8*)&kv_s[(wc * 32 + j * 16 + lr) * 72 + kk * 32 + lkq * 8];
            #pragma unroll
            for (int i = 0; i < 4; ++i)
                #pragma unroll
                for (int j = 0; j < 2; ++j)
                    acc[i][j] = __builtin_amdgcn_mfma_f32_16x16x32_bf16(
                        af[i], bfv[j], acc[i][j], 0, 0, 0);
        }
    }

    const int cq = 2 * bx + wr;
    float off[2];
    #pragma unroll
    for (int j = 0; j < 2; ++j) {
        const int cl = wc * 32 + j * 16 + lr;
        float o = 0.f;
        for (int q = 0; q < cq; ++q)
            o += aux[((size_t)b * 16 + q) * C_DIM + h * HS + cl];
        off[j] = o;
    }

    // ---- epilogue via LDS staging over dead repl (all repl reads done) ----
    __syncthreads();
    char* const Cc = (char*)repl;   // 128 rows x 64 ch bf16 = 16KB
    #pragma unroll
    for (int i = 0; i < 4; ++i) {
        const int rbl = wr * 64 + i * 16 + lkq * 4;
        #pragma unroll
        for (int rg = 0; rg < 4; ++rg) {
            const int row_l = rbl + rg;
            const int t = t0 + row_l;
            const float bet = beta[h * T_CTX + t];
            const size_t row_off = ((size_t)(b * T_CTX + t)) * C_DIM + h * HS;
            #pragma unroll
            for (int j = 0; j < 2; ++j) {
                const int cl = wc * 32 + j * 16 + lr;
                const float sk = sumk[row_off + cl] + off[j];
                const float sr = bf2f(sigr[row_off + cl]);
                const int byte = row_l * 128 + ((cl * 2) ^ ((row_l & 7) << 4));
                *(unsigned short*)(Cc + byte) = f2bf(sr * bet * acc[i][j][rg] / sk);
            }
        }
    }
    __syncthreads();
    // 8 lanes x 16B = 128B contiguous per row; 4 rounds x 32 rows
    #pragma unroll
    for (int it = 0; it < 4; ++it) {
        const int row_l = (tid >> 3) + it * 32;
        const int k = tid & 7;
        const int byte = row_l * 128 + ((k * 16) ^ ((row_l & 7) << 4));
        const u16x8 v = *(const u16x8*)(Cc + byte);
        *(u16x8*)(rwkv + ((size_t)(b * T_CTX + t0 + row_l)) * C_DIM + h * HS + k * 8) = v;
    }
}

// ---------------------------------------------------------------------------
extern "C" void kernel_launch(void* const* d_in, const int* in_sizes, int n_in,
                              void* d_out, int out_size, void* d_ws, size_t ws_size,
                              hipStream_t stream)
{
    const float* x     = (const float*)d_in[0];
    const float* tw    = (const float*)d_in[1];
    const float* alpha = (const float*)d_in[2];
    const float* beta  = (const float*)d_in[3];
    const float* gamma = (const float*)d_in[4];
    const float* Wk    = (const float*)d_in[5];
    const float* bk    = (const float*)d_in[6];
    const float* Wv    = (const float*)d_in[7];
    const float* bv    = (const float*)d_in[8];
    const float* Wr    = (const float*)d_in[9];
    const float* br    = (const float*)d_in[10];
    const float* Wo    = (const float*)d_in[11];
    const float* bo    = (const float*)d_in[12];
    float* out = (float*)d_out;

    // workspace layout (bytes), max 128M:
    //  [0,32M)   expk fp32    -> rwkv bf16 [0,16M) after cumsum
    //  [32,48M)  v bf16
    //  [48,56M)  weights bf16 (Wk,Wv,Wr,Wo stacked @ 2MB each)
    //  [56,56.5M) aux (raw 64-chunk totals)
    //  [64,96M)  sumk fp32 (chunk-local)  (xs bf16 overlays [64,80M) during proj)
    //  [96,112M) sigr bf16
    //  [112,128M) kvT bf16
    char* W = (char*)d_ws;
    float* expk          = (float*)W;
    unsigned short* rwkv = (unsigned short*)W;
    unsigned short* vbf  = (unsigned short*)(W + (32ull << 20));
    unsigned short* wbf  = (unsigned short*)(W + (48ull << 20));
    float* aux           = (float*)(W + (56ull << 20));
    float* sumk          = (float*)(W + (64ull << 20));
    unsigned short* xs   = (unsigned short*)(W + (64ull << 20));
    unsigned short* sigr = (unsigned short*)(W + (96ull << 20));
    unsigned short* kvT  = (unsigned short*)(W + (112ull << 20));

    const size_t WSZ = (size_t)C_DIM * C_DIM;

    convert_all<<<dim3(12288), 256, 0, stream>>>(x, xs, Wk, Wv, Wr, Wo, wbf);

    // k,v,r projections as one N=3072 GEMM (W stacked), XCD-swizzled
    mfma_gemm64<<<dim3(1536), 256, 0, stream>>>(
        xs, wbf, bk, bv, br, expk, vbf, sigr, gamma, 1);

    cumsum_chunk<<<dim3(4, 16, 8), 256, 0, stream>>>(expk, vbf, alpha, sumk, kvT, aux);

    wkv_mfma<<<dim3(8, 16, 8), 256, 0, stream>>>(
        kvT, sumk, sigr, tw, beta, aux, rwkv);

    // output projection + gamma
    mfma_gemm64<<<dim3(512), 256, 0, stream>>>(
        rwkv, wbf + 3 * WSZ, bo, nullptr, nullptr,
        out, nullptr, nullptr, gamma, 0);
}

// Round 8
// 252.506 us; speedup vs baseline: 1.1308x; 1.0277x over previous
//
#include <hip/hip_runtime.h>
#include <hip/hip_bf16.h>
#include <cstddef>
#include <cstdint>

#define B_SZ   8
#define T_CTX  1024
#define C_DIM  1024
#define H_NUM  16
#define HS     64
#define M_ROWS (B_SZ * T_CTX)

typedef __attribute__((ext_vector_type(8))) short bf16x8;
typedef __attribute__((ext_vector_type(8))) unsigned short u16x8;
typedef __attribute__((ext_vector_type(4))) float f32x4;

static __device__ inline unsigned short f2bf(float f) {
    __hip_bfloat16 h = __float2bfloat16(f);
    return __builtin_bit_cast(unsigned short, h);
}
static __device__ inline float bf2f(unsigned short u) {
    unsigned int v = ((unsigned int)u) << 16;
    return __builtin_bit_cast(float, v);
}
static __device__ inline void gld16(const void* g, void* l) {
    __builtin_amdgcn_global_load_lds((const __attribute__((address_space(1))) void*)g,
                                     (__attribute__((address_space(3))) void*)l,
                                     16, 0, 0);
}

// ---------------------------------------------------------------------------
// Fused conversion: blocks [0,8192) do x->xs (bf16, time-shifted);
// blocks [8192,12288) do the 4 weight matrices -> stacked bf16.
// ---------------------------------------------------------------------------
__global__ __launch_bounds__(256)
void convert_all(const float* __restrict__ x, unsigned short* __restrict__ xs,
                 const float* __restrict__ Wk, const float* __restrict__ Wv,
                 const float* __restrict__ Wr, const float* __restrict__ Wo,
                 unsigned short* __restrict__ wdst)
{
    const int bid = blockIdx.x;
    if (bid < 8192) {
        const int idx = (bid * 256 + threadIdx.x) * 4;
        const int m = idx >> 10;
        const int c = idx & 1023;
        float4 v;
        if (c < 512) {
            const int t = m & (T_CTX - 1);
            if (t == 0) v = make_float4(0.f, 0.f, 0.f, 0.f);
            else        v = *(const float4*)(x + (size_t)(m - 1) * C_DIM + c);
        } else {
            v = *(const float4*)(x + idx);
        }
        ushort4 o;
        o.x = f2bf(v.x); o.y = f2bf(v.y); o.z = f2bf(v.z); o.w = f2bf(v.w);
        *(ushort4*)(xs + idx) = o;
    } else {
        const int wid = bid - 8192;
        const int z = wid >> 10;
        const float* src = (z == 0) ? Wk : (z == 1) ? Wv : (z == 2) ? Wr : Wo;
        const int idx = ((wid & 1023) * 256 + threadIdx.x) * 4;
        const float4 v = *(const float4*)(src + idx);
        ushort4 o;
        o.x = f2bf(v.x); o.y = f2bf(v.y); o.z = f2bf(v.z); o.w = f2bf(v.w);
        *(ushort4*)(wdst + (size_t)z * (C_DIM * C_DIM) + idx) = o;
    }
}

// ---------------------------------------------------------------------------
// bf16 MFMA GEMM, BK=64, XOR-swizzled LDS (slot = chunk ^ (row&7)).
// ROUND-0 PROVEN CONFIG: __launch_bounds__(256,2), 32 KiB LDS — frozen.
// r7: bf16 modes (1,2) write through an LDS-transposed epilogue: 256B
// contiguous row stores (was 32B partial-granule, ~2x write amplification).
// r8 fix: staging swizzle key is ((row>>2)&7)<<5 (was (row&7)<<5, which
// mapped lkq row-groups 4-apart to the SAME banks -> 524K conflicts).
// Now lkq groups partition banks 0-7/8-15/16-23/24-31 -> conflict-free.
// multi=1: W stacked [3072x1024]; mode = n0>>10:
//   0: exp(clip)->fp32 expk ; 1: identity->bf16 v ; 2: sigmoid->bf16 sigr
// multi=0: mode 3: (v+bias)*gamma[t] -> fp32 out (64B segments, unchanged)
// Block swizzle: d -> y=((d&7)<<3)|((d>>3)&7), x=d>>6 (XCD L2 locality).
// ---------------------------------------------------------------------------
__global__ __launch_bounds__(256, 2)
void mfma_gemm64(const unsigned short* __restrict__ A,
                 const unsigned short* __restrict__ Wb,
                 const float* __restrict__ b0, const float* __restrict__ b1,
                 const float* __restrict__ b2,
                 void* __restrict__ o0, void* __restrict__ o1, void* __restrict__ o2,
                 const float* __restrict__ gamma, int multi)
{
    const int d  = blockIdx.x;
    const int y  = ((d & 7) << 3) | ((d >> 3) & 7);
    const int xb = d >> 6;
    const int m0 = y * 128, n0 = xb * 128;

    int mode, ncol0;
    const float* bias;
    void* out;
    if (multi) {
        const int z = n0 >> 10;
        mode = z;
        ncol0 = n0 & 1023;
        bias = (z == 0) ? b0 : (z == 1) ? b1 : b2;
        out  = (z == 0) ? o0 : (z == 1) ? o1 : o2;
    } else {
        mode = 3; ncol0 = n0; bias = b0; out = o0;
    }

    // single 32KB buffer: [0,8192) = A-tile, [8192,16384) = B-tile;
    // whole buffer reused as the bf16 C-staging area in the epilogue.
    __shared__ unsigned short Sh[2 * 128 * 64];

    const int tid = threadIdx.x;
    const int w = tid >> 6, l = tid & 63;

    // staging: wave w covers rows [w*32, w*32+32) in 4 rounds of 8 rows.
    // lane l -> row offset r8 = l>>3, fetches global k-chunk (l&7)^r8 so the
    // contiguous LDS write leaves slot s of row R holding chunk s^(R&7).
    const int r8  = l >> 3;
    const int c16 = ((l & 7) ^ r8) * 8;
    const unsigned short* gA = A  + (size_t)(m0 + w * 32 + r8) * C_DIM + c16;
    const unsigned short* gB = Wb + (size_t)(n0 + w * 32 + r8) * C_DIM + c16;
    char* lA = (char*)Sh + (w * 32) * 128;
    char* lB = (char*)Sh + 16384 + (w * 32) * 128;

    const int wr = w >> 1, wc = w & 1;
    const int lr = l & 15, lkq = l >> 4;
    const int x7 = lr & 7;

    f32x4 acc[4][4];
    #pragma unroll
    for (int i = 0; i < 4; ++i)
        #pragma unroll
        for (int j = 0; j < 4; ++j) acc[i][j] = (f32x4){0.f, 0.f, 0.f, 0.f};

    for (int k0 = 0; k0 < C_DIM; k0 += 64) {
        #pragma unroll
        for (int r = 0; r < 4; ++r) {
            gld16(gA + k0 + (size_t)r * 8 * C_DIM, lA + r * 8 * 128);
            gld16(gB + k0 + (size_t)r * 8 * C_DIM, lB + r * 8 * 128);
        }
        __syncthreads();

        bf16x8 af[2][4], bfv[2][4];
        #pragma unroll
        for (int ks = 0; ks < 2; ++ks) {
            const int slot = ((ks * 4 + lkq) ^ x7) * 8;   // swizzled k-offset
            #pragma unroll
            for (int i = 0; i < 4; ++i)
                af[ks][i] = *(const bf16x8*)&Sh[(wr * 64 + i * 16 + lr) * 64 + slot];
            #pragma unroll
            for (int j = 0; j < 4; ++j)
                bfv[ks][j] = *(const bf16x8*)&Sh[8192 + (wc * 64 + j * 16 + lr) * 64 + slot];
        }
        #pragma unroll
        for (int ks = 0; ks < 2; ++ks)
            #pragma unroll
            for (int i = 0; i < 4; ++i)
                #pragma unroll
                for (int j = 0; j < 4; ++j)
                    acc[i][j] = __builtin_amdgcn_mfma_f32_16x16x32_bf16(
                        af[ks][i], bfv[ks][j], acc[i][j], 0, 0, 0);
        __syncthreads();
    }

    // epilogue: C/D layout col=lane&15, row=(lane>>4)*4+reg
    if (mode == 1 || mode == 2) {
        // ---- bf16 modes: LDS-transposed coalesced stores ----
        char* const Cs = (char*)Sh;   // 32KB, dead after final K-loop barrier
        #pragma unroll
        for (int j = 0; j < 4; ++j) {
            const int col_l = wc * 64 + j * 16 + lr;
            const float bz = bias[ncol0 + col_l];
            #pragma unroll
            for (int i = 0; i < 4; ++i) {
                const int rbl = wr * 64 + i * 16 + lkq * 4;
                #pragma unroll
                for (int r = 0; r < 4; ++r) {
                    const int row_l = rbl + r;
                    float v = acc[i][j][r] + bz;
                    if (mode == 2) v = 1.f / (1.f + __expf(-v));
                    const int byte = row_l * 256 + ((col_l * 2) ^ (((row_l >> 2) & 7) << 5));
                    *(unsigned short*)(Cs + byte) = f2bf(v);
                }
            }
        }
        __syncthreads();
        // 16 lanes x 16B = 256B contiguous per output row; 8 rounds x 16 rows
        #pragma unroll
        for (int it = 0; it < 8; ++it) {
            const int row_l = (tid >> 4) + it * 16;
            const int k = tid & 15;
            const int byte = row_l * 256 + ((k * 16) ^ (((row_l >> 2) & 7) << 5));
            const u16x8 v = *(const u16x8*)(Cs + byte);
            *(u16x8*)((unsigned short*)out + (size_t)(m0 + row_l) * C_DIM + ncol0 + k * 8) = v;
        }
    } else {
        // ---- fp32 modes (0,3): original path (64B segments, no amplification)
        #pragma unroll
        for (int j = 0; j < 4; ++j) {
            const int col = ncol0 + wc * 64 + j * 16 + lr;
            const float bz = bias[col];
            #pragma unroll
            for (int i = 0; i < 4; ++i) {
                const int rb = m0 + wr * 64 + i * 16 + lkq * 4;
                #pragma unroll
                for (int r = 0; r < 4; ++r) {
                    const int row = rb + r;
                    float v = acc[i][j][r] + bz;
                    if (mode == 0)      v = __expf(fminf(fmaxf(v, -60.f), 30.f));
                    else                v *= gamma[row & (T_CTX - 1)];
                    ((float*)out)[(size_t)row * C_DIM + col] = v;
                }
            }
        }
    }
}

// ---------------------------------------------------------------------------
// Chunk-local cumsum of expk + kvT[b,h,c,u] = bf16(expk * v * alpha[h,u]).
// 64-row chunks (q in [0,16)); static u16x8 indexing (rule #20), 8-deep MLP.
// kvT stores transposed through LDS (r6 win): wave stages [64c][64u] tile
// (stride 68 -> <=4-way aliasing), writes 8x128B contiguous runs.
// sumk holds CHUNK-LOCAL prefix sums; aux[b,q,n] = raw 64-chunk totals.
// ---------------------------------------------------------------------------
__global__ __launch_bounds__(256)
void cumsum_chunk(const float* __restrict__ expk, const unsigned short* __restrict__ vbf,
                  const float* __restrict__ alpha,
                  float* __restrict__ sumk, unsigned short* __restrict__ kvT,
                  float* __restrict__ aux)
{
    __shared__ unsigned short kvs[4][64 * 68];
    const int tid = threadIdx.x;
    const int w = tid >> 6, l = tid & 63;
    const int n = blockIdx.x * 256 + tid;    // channel; c = n&63 = l
    const int q = blockIdx.y;                // 16 chunks of 64 rows
    const int b = blockIdx.z;
    const int h = n >> 6;                    // = blockIdx.x*4 + w (wave-uniform)
    const size_t base = ((size_t)b * T_CTX + q * 64) * C_DIM + n;
    const float* arow = alpha + h * T_CTX + q * 64;

    float s = 0.f;
    for (int g = 0; g < 8; ++g) {
        u16x8 buf;
        #pragma unroll
        for (int k = 0; k < 8; ++k) {
            const int i = g * 8 + k;
            const size_t idx = base + (size_t)i * C_DIM;
            const float e  = expk[idx];
            const float vv = bf2f(vbf[idx]);
            s += e;
            sumk[idx] = s;
            buf[k] = f2bf(e * vv * arow[i]);
        }
        *(u16x8*)&kvs[w][l * 68 + g * 8] = buf;
    }
    aux[((size_t)b * 16 + q) * C_DIM + n] = s;

    __syncthreads();

    // transposed write-out: lane l covers row c2=(l>>3)+r*8, u-slice (l&7)*8.
    const int u8 = (l & 7) * 8;
    #pragma unroll
    for (int r = 0; r < 8; ++r) {
        const int c2 = (l >> 3) + r * 8;
        const u16x8 v = *(const u16x8*)&kvs[w][c2 * 68 + u8];
        *(u16x8*)(kvT + (((size_t)b * H_NUM + h) * HS + c2) * T_CTX + q * 64 + u8) = v;
    }
}

// ---------------------------------------------------------------------------
// wkv via MFMA (Toeplitz):  wkv[t,c] = sum_u twx[1023-t+u] * kvT[c,u]
// A-frags from 8 shift-replicas of twx in LDS; B = kvT tile in padded LDS.
// Epilogue: rwkv = sigr * beta[t] * acc / (sumk_chunk + prefix(aux))  (bf16)
// r8: LOAD-BALANCED chunk pairing. Block bxp processes t-tiles bxp and
// 7-bxp sequentially: per-tile step count is 2*bx+2, so the pair is a
// constant 18 steps -> every block does equal work (was 2..16, 8x skew).
// Grid (4,16,8) = 512 blocks = 2/CU, all co-resident (LDS 46.4KB -> 3/CU cap).
// Epilogue staging moved to a dedicated cst buffer (repl must survive for
// pass 2). Store swizzle key ((row>>2)&3)<<5: lkq row-groups partition
// banks (the r7 (row&7)<<4 key overlapped 4-bank shifts -> conflicts).
// ---------------------------------------------------------------------------
#define REPL_STRIDE 1176
#define REPL_USED   1168

__global__ __launch_bounds__(256)
void wkv_mfma(const unsigned short* __restrict__ kvT,
              const float* __restrict__ sumk,
              const unsigned short* __restrict__ sigr,
              const float* __restrict__ tw, const float* __restrict__ beta,
              const float* __restrict__ aux,
              unsigned short* __restrict__ rwkv)
{
    __shared__ unsigned short repl[8 * REPL_STRIDE];
    __shared__ unsigned short kv_s[64 * 72];
    __shared__ unsigned short tw_s[1024];
    __shared__ unsigned short cst[128 * 64];   // epilogue staging (16KB)

    const int tid = threadIdx.x;
    const int bxp = blockIdx.x;              // 0..3 -> pair (bxp, 7-bxp)
    const int h  = blockIdx.y;
    const int b  = blockIdx.z;

    {
        const int i = tid * 4;
        const float4 v = *(const float4*)(tw + h * T_CTX + i);
        ushort4 o;
        o.x = f2bf(v.x); o.y = f2bf(v.y); o.z = f2bf(v.z); o.w = f2bf(v.w);
        *(ushort4*)&tw_s[i] = o;
    }
    __syncthreads();

    #pragma unroll
    for (int r = 0; r < 8; ++r)
        for (int i = tid; i < REPL_USED; i += 256) {
            const int src = i + r;
            repl[r * REPL_STRIDE + i] = (src < 1024) ? tw_s[src] : (unsigned short)0;
        }

    const int w = tid >> 6, l = tid & 63;
    const int wr = w >> 1, wc = w & 1;
    const int lr = l & 15, lkq = l >> 4;
    const int r    = (7 - lr) & 7;
    const char* repl_c = (const char*)repl;

    const int srow = tid >> 2;
    const int ucol = (tid & 3) * 16;
    const unsigned short* gkv = kvT + (((size_t)b * H_NUM + h) * HS + srow) * T_CTX + ucol;
    unsigned short* skv = &kv_s[srow * 72 + ucol];

    for (int pass = 0; pass < 2; ++pass) {
        const int bx = pass ? (7 - bxp) : bxp;
        const int t0 = bx * 128;
        const int S0 = 1023 - t0 - wr * 64 - lr + lkq * 8;
        const int abase = 2 * S0 + (2 * REPL_STRIDE - 2) * r;

        f32x4 acc[4][2];
        #pragma unroll
        for (int i = 0; i < 4; ++i) {
            acc[i][0] = (f32x4){0.f, 0.f, 0.f, 0.f};
            acc[i][1] = (f32x4){0.f, 0.f, 0.f, 0.f};
        }

        const int nsteps = t0 / 64 + 2;
        u16x8 q0 = *(const u16x8*)(gkv);
        u16x8 q1 = *(const u16x8*)(gkv + 8);
        for (int ks = 0; ks < nsteps; ++ks) {
            __syncthreads();
            *(u16x8*)skv       = q0;
            *(u16x8*)(skv + 8) = q1;
            __syncthreads();
            if (ks + 1 < nsteps) {
                const int un = (ks + 1) * 64;
                q0 = *(const u16x8*)(gkv + un);
                q1 = *(const u16x8*)(gkv + un + 8);
            }

            const int ub = abase + 2 * (ks * 64);
            #pragma unroll
            for (int kk = 0; kk < 2; ++kk) {
                bf16x8 af[4], bfv[2];
                #pragma unroll
                for (int i = 0; i < 4; ++i)
                    af[i] = *(const bf16x8*)(repl_c + (ub + kk * 64 - i * 32));
                #pragma unroll
                for (int j = 0; j < 2; ++j)
                    bfv[j] = *(const bf16x8*)&kv_s[(wc * 32 + j * 16 + lr) * 72 + kk * 32 + lkq * 8];
                #pragma unroll
                for (int i = 0; i < 4; ++i)
                    #pragma unroll
                    for (int j = 0; j < 2; ++j)
                        acc[i][j] = __builtin_amdgcn_mfma_f32_16x16x32_bf16(
                            af[i], bfv[j], acc[i][j], 0, 0, 0);
            }
        }

        // aux prefix: this thread's rows live in 64-chunk (2*bx + wr)
        const int cq = 2 * bx + wr;
        float off[2];
        #pragma unroll
        for (int j = 0; j < 2; ++j) {
            const int cl = wc * 32 + j * 16 + lr;
            float o = 0.f;
            for (int q = 0; q < cq; ++q)
                o += aux[((size_t)b * 16 + q) * C_DIM + h * HS + cl];
            off[j] = o;
        }

        // ---- epilogue via dedicated cst staging ----
        char* const Cc = (char*)cst;   // 128 rows x 64 ch bf16 = 16KB
        #pragma unroll
        for (int i = 0; i < 4; ++i) {
            const int rbl = wr * 64 + i * 16 + lkq * 4;
            #pragma unroll
            for (int rg = 0; rg < 4; ++rg) {
                const int row_l = rbl + rg;
                const int t = t0 + row_l;
                const float bet = beta[h * T_CTX + t];
                const size_t row_off = ((size_t)(b * T_CTX + t)) * C_DIM + h * HS;
                #pragma unroll
                for (int j = 0; j < 2; ++j) {
                    const int cl = wc * 32 + j * 16 + lr;
                    const float sk = sumk[row_off + cl] + off[j];
                    const float sr = bf2f(sigr[row_off + cl]);
                    const int byte = row_l * 128 + ((cl * 2) ^ (((row_l >> 2) & 3) << 5));
                    *(unsigned short*)(Cc + byte) = f2bf(sr * bet * acc[i][j][rg] / sk);
                }
            }
        }
        __syncthreads();
        // 8 lanes x 16B = 128B contiguous per row; 4 rounds x 32 rows
        #pragma unroll
        for (int it = 0; it < 4; ++it) {
            const int row_l = (tid >> 3) + it * 32;
            const int k = tid & 7;
            const int byte = row_l * 128 + ((k * 16) ^ (((row_l >> 2) & 3) << 5));
            const u16x8 v = *(const u16x8*)(Cc + byte);
            *(u16x8*)(rwkv + ((size_t)(b * T_CTX + t0 + row_l)) * C_DIM + h * HS + k * 8) = v;
        }
        __syncthreads();
    }
}

// ---------------------------------------------------------------------------
extern "C" void kernel_launch(void* const* d_in, const int* in_sizes, int n_in,
                              void* d_out, int out_size, void* d_ws, size_t ws_size,
                              hipStream_t stream)
{
    const float* x     = (const float*)d_in[0];
    const float* tw    = (const float*)d_in[1];
    const float* alpha = (const float*)d_in[2];
    const float* beta  = (const float*)d_in[3];
    const float* gamma = (const float*)d_in[4];
    const float* Wk    = (const float*)d_in[5];
    const float* bk    = (const float*)d_in[6];
    const float* Wv    = (const float*)d_in[7];
    const float* bv    = (const float*)d_in[8];
    const float* Wr    = (const float*)d_in[9];
    const float* br    = (const float*)d_in[10];
    const float* Wo    = (const float*)d_in[11];
    const float* bo    = (const float*)d_in[12];
    float* out = (float*)d_out;

    // workspace layout (bytes), max 128M:
    //  [0,32M)   expk fp32    -> rwkv bf16 [0,16M) after cumsum
    //  [32,48M)  v bf16
    //  [48,56M)  weights bf16 (Wk,Wv,Wr,Wo stacked @ 2MB each)
    //  [56,56.5M) aux (raw 64-chunk totals)
    //  [64,96M)  sumk fp32 (chunk-local)  (xs bf16 overlays [64,80M) during proj)
    //  [96,112M) sigr bf16
    //  [112,128M) kvT bf16
    char* W = (char*)d_ws;
    float* expk          = (float*)W;
    unsigned short* rwkv = (unsigned short*)W;
    unsigned short* vbf  = (unsigned short*)(W + (32ull << 20));
    unsigned short* wbf  = (unsigned short*)(W + (48ull << 20));
    float* aux           = (float*)(W + (56ull << 20));
    float* sumk          = (float*)(W + (64ull << 20));
    unsigned short* xs   = (unsigned short*)(W + (64ull << 20));
    unsigned short* sigr = (unsigned short*)(W + (96ull << 20));
    unsigned short* kvT  = (unsigned short*)(W + (112ull << 20));

    const size_t WSZ = (size_t)C_DIM * C_DIM;

    convert_all<<<dim3(12288), 256, 0, stream>>>(x, xs, Wk, Wv, Wr, Wo, wbf);

    // k,v,r projections as one N=3072 GEMM (W stacked), XCD-swizzled
    mfma_gemm64<<<dim3(1536), 256, 0, stream>>>(
        xs, wbf, bk, bv, br, expk, vbf, sigr, gamma, 1);

    cumsum_chunk<<<dim3(4, 16, 8), 256, 0, stream>>>(expk, vbf, alpha, sumk, kvT, aux);

    // load-balanced: each block does chunk pair (bx, 7-bx) = constant 18 steps
    wkv_mfma<<<dim3(4, 16, 8), 256, 0, stream>>>(
        kvT, sumk, sigr, tw, beta, aux, rwkv);

    // output projection + gamma
    mfma_gemm64<<<dim3(512), 256, 0, stream>>>(
        rwkv, wbf + 3 * WSZ, bo, nullptr, nullptr,
        out, nullptr, nullptr, gamma, 0);
}